// Round 4
// baseline (615.342 us; speedup 1.0000x reference)
//
#include <hip/hip_runtime.h>

#define MSG 64
#define NCOMBO 476   // 119 atom ids * 4 bond ids
#define BSHIFT 6     // bucket = dst >> 6  (64 nodes per bucket)

typedef _Float16 h4 __attribute__((ext_vector_type(4)));

// tAB[c][i] = bias[i] + atom[c>>2] @ W[0:64] + bond[c&3] @ W[64:80]   (W ld=64), fp16 out
__global__ void build_tab_kernel(const float* __restrict__ atom, const float* __restrict__ bond,
                                 const float* __restrict__ W, const float* __restrict__ bias,
                                 _Float16* __restrict__ tAB) {
    int t = blockIdx.x * blockDim.x + threadIdx.x;
    if (t >= NCOMBO * MSG) return;
    int i = t & 63, c = t >> 6, xa = c >> 2, ea = c & 3;
    float s = bias[i];
    for (int k = 0; k < 64; ++k) s = fmaf(atom[xa * 64 + k], W[k * 64 + i], s);
    for (int k = 0; k < 16; ++k) s = fmaf(bond[ea * 16 + k], W[(64 + k) * 64 + i], s);
    tAB[t] = (_Float16)s;
}

__global__ void hist_kernel(const int* __restrict__ ei, int E, int* __restrict__ cnt) {
    int e = blockIdx.x * blockDim.x + threadIdx.x;
    if (e < E) atomicAdd(&cnt[ei[E + e]], 1);
}

// block-level inclusive scan (1024/block) + block sums
__global__ void scan1_kernel(const int* __restrict__ cnt, int* __restrict__ incl,
                             int* __restrict__ bsum, int N) {
    int i = blockIdx.x * 1024 + threadIdx.x;
    int v = (i < N) ? cnt[i] : 0;
    int lane = threadIdx.x & 63, w = threadIdx.x >> 6;
    int s = v;
    for (int off = 1; off < 64; off <<= 1) { int t = __shfl_up(s, off); if (lane >= off) s += t; }
    __shared__ int wsum[16];
    if (lane == 63) wsum[w] = s;
    __syncthreads();
    if (w == 0 && lane < 16) {
        int t = wsum[lane];
        for (int off = 1; off < 16; off <<= 1) { int u = __shfl_up(t, off); if (lane >= off) t += u; }
        wsum[lane] = t;
    }
    __syncthreads();
    if (w > 0) s += wsum[w - 1];
    if (i < N) incl[i] = s;
    if (threadIdx.x == 1023) bsum[blockIdx.x] = s;
}

__global__ void scan2_kernel(int* __restrict__ bsum, int nb) {
    if (threadIdx.x == 0 && blockIdx.x == 0) {
        int run = 0;
        for (int b = 0; b < nb; ++b) { int t = bsum[b]; bsum[b] = run; run += t; }
    }
}

__global__ void scan3_kernel(const int* __restrict__ incl, const int* __restrict__ bsum,
                             int* __restrict__ off, int N) {
    int i = blockIdx.x * 1024 + threadIdx.x;
    if (i < N) off[i + 1] = incl[i] + bsum[blockIdx.x];
    if (i == 0) off[0] = 0;
}

__global__ void binit_kernel(const int* __restrict__ offs, int* __restrict__ bcur, int K) {
    int b = blockIdx.x * blockDim.x + threadIdx.x;
    if (b < K) bcur[b] = offs[b << BSHIFT];
}

// Phase 1: scatter edge payload into its dst-bucket region (sequential front per bucket).
// payload = (src | combo<<17) << 17 | dst   (43 bits)
__global__ void bucket_scatter_kernel(const int* __restrict__ ei, const int* __restrict__ x,
                                      const int* __restrict__ eattr, int E,
                                      int* __restrict__ bcur, unsigned long long* __restrict__ aux) {
    int e = blockIdx.x * blockDim.x + threadIdx.x;
    if (e >= E) return;
    int s = ei[e], d = ei[E + e];
    unsigned pw = (unsigned)s | ((unsigned)(x[s] * 4 + eattr[e]) << 17);
    int p = atomicAdd(&bcur[d >> BSHIFT], 1);
    aux[p] = ((unsigned long long)pw << 17) | (unsigned)d;
}

// Phase 2: one block per bucket; place entries at final CSR positions via LDS cursors.
__global__ void bucket_place_kernel(const unsigned long long* __restrict__ aux,
                                    const int* __restrict__ offs,
                                    unsigned* __restrict__ packed, int N) {
    __shared__ int lcur[64];
    int b = blockIdx.x;
    int n0 = b << BSHIFT;
    int endn = min(n0 + 64, N);
    if (threadIdx.x < 64 && n0 + threadIdx.x < N) lcur[threadIdx.x] = offs[n0 + threadIdx.x];
    __syncthreads();
    int start = offs[n0];
    int end = offs[endn];
    for (int idx = start + threadIdx.x; idx < end; idx += blockDim.x) {
        unsigned long long a = aux[idx];
        int d = (int)(a & 0x1FFFFu);
        unsigned pw = (unsigned)(a >> 17);
        int p = atomicAdd(&lcur[d & 63], 1);
        packed[p] = pw;
    }
}

// 16 lanes per node (h4/float4 per lane), 16 nodes per 256-thread block.
// acc = sum_{in-edges} relu(tAB[combo] + agg2[src]).   tAB/agg2/out in fp16, math fp32.
// MODE 0: no agg2, fused epilogue GEMM; MODE 1: agg2 + fused GEMM; MODE 2: agg2, raw out.
template <int MODE>
__global__ __launch_bounds__(256) void gather_kernel(
    const unsigned* __restrict__ packed, const int* __restrict__ off,
    const _Float16* __restrict__ tAB, const _Float16* __restrict__ agg2,
    const float* __restrict__ Wagg, _Float16* __restrict__ out, int N)
{
    __shared__ float Ws[64 * 64];
    __shared__ float rowbuf[16][68];   // stride 68 de-conflicts per-group broadcast
    if (MODE < 2)
        for (int idx = threadIdx.x; idx < 64 * 64; idx += 256) Ws[idx] = Wagg[idx];
    int t = blockIdx.x * 256 + threadIdx.x;
    int v = t >> 4;                    // node
    int j = threadIdx.x & 15;          // feature quad
    int w = threadIdx.x >> 4;          // group in block
    const h4* tAB4 = (const h4*)tAB;
    const h4* agg4 = (const h4*)agg2;
    float ax = 0.f, ay = 0.f, az = 0.f, aw = 0.f;
    if (v < N) {
        int e = off[v], end = off[v + 1];
        for (; e + 3 < end; e += 4) {
            unsigned p0 = packed[e], p1 = packed[e + 1], p2 = packed[e + 2], p3 = packed[e + 3];
            h4 t0 = tAB4[(p0 >> 17) * 16 + j];
            h4 t1 = tAB4[(p1 >> 17) * 16 + j];
            h4 t2 = tAB4[(p2 >> 17) * 16 + j];
            h4 t3 = tAB4[(p3 >> 17) * 16 + j];
            float m0x = (float)t0.x, m0y = (float)t0.y, m0z = (float)t0.z, m0w = (float)t0.w;
            float m1x = (float)t1.x, m1y = (float)t1.y, m1z = (float)t1.z, m1w = (float)t1.w;
            float m2x = (float)t2.x, m2y = (float)t2.y, m2z = (float)t2.z, m2w = (float)t2.w;
            float m3x = (float)t3.x, m3y = (float)t3.y, m3z = (float)t3.z, m3w = (float)t3.w;
            if (MODE) {
                h4 a0 = agg4[(p0 & 0x1FFFFu) * 16 + j];
                h4 a1 = agg4[(p1 & 0x1FFFFu) * 16 + j];
                h4 a2 = agg4[(p2 & 0x1FFFFu) * 16 + j];
                h4 a3 = agg4[(p3 & 0x1FFFFu) * 16 + j];
                m0x += (float)a0.x; m0y += (float)a0.y; m0z += (float)a0.z; m0w += (float)a0.w;
                m1x += (float)a1.x; m1y += (float)a1.y; m1z += (float)a1.z; m1w += (float)a1.w;
                m2x += (float)a2.x; m2y += (float)a2.y; m2z += (float)a2.z; m2w += (float)a2.w;
                m3x += (float)a3.x; m3y += (float)a3.y; m3z += (float)a3.z; m3w += (float)a3.w;
            }
            ax += fmaxf(m0x, 0.f) + fmaxf(m1x, 0.f) + fmaxf(m2x, 0.f) + fmaxf(m3x, 0.f);
            ay += fmaxf(m0y, 0.f) + fmaxf(m1y, 0.f) + fmaxf(m2y, 0.f) + fmaxf(m3y, 0.f);
            az += fmaxf(m0z, 0.f) + fmaxf(m1z, 0.f) + fmaxf(m2z, 0.f) + fmaxf(m3z, 0.f);
            aw += fmaxf(m0w, 0.f) + fmaxf(m1w, 0.f) + fmaxf(m2w, 0.f) + fmaxf(m3w, 0.f);
        }
        for (; e < end; ++e) {
            unsigned p0 = packed[e];
            h4 t0 = tAB4[(p0 >> 17) * 16 + j];
            float m0x = (float)t0.x, m0y = (float)t0.y, m0z = (float)t0.z, m0w = (float)t0.w;
            if (MODE) {
                h4 a0 = agg4[(p0 & 0x1FFFFu) * 16 + j];
                m0x += (float)a0.x; m0y += (float)a0.y; m0z += (float)a0.z; m0w += (float)a0.w;
            }
            ax += fmaxf(m0x, 0.f);
            ay += fmaxf(m0y, 0.f);
            az += fmaxf(m0z, 0.f);
            aw += fmaxf(m0w, 0.f);
        }
    }
    if (MODE == 2) {
        if (v < N) {
            h4 o; o.x = (_Float16)ax; o.y = (_Float16)ay; o.z = (_Float16)az; o.w = (_Float16)aw;
            ((h4*)out)[(long long)v * 16 + j] = o;
        }
        return;
    }
    rowbuf[w][j * 4 + 0] = ax;
    rowbuf[w][j * 4 + 1] = ay;
    rowbuf[w][j * 4 + 2] = az;
    rowbuf[w][j * 4 + 3] = aw;
    __syncthreads();
    if (v >= N) return;
    const float4* Ws4 = (const float4*)Ws;
    float sx = 0.f, sy = 0.f, sz = 0.f, sw = 0.f;
#pragma unroll
    for (int k = 0; k < 64; ++k) {
        float r = rowbuf[w][k];
        float4 wv = Ws4[k * 16 + j];
        sx = fmaf(r, wv.x, sx);
        sy = fmaf(r, wv.y, sy);
        sz = fmaf(r, wv.z, sz);
        sw = fmaf(r, wv.w, sw);
    }
    h4 o; o.x = (_Float16)sx; o.y = (_Float16)sy; o.z = (_Float16)sz; o.w = (_Float16)sw;
    ((h4*)out)[(long long)v * 16 + j] = o;
}

// batch is sorted: run-length accumulate, flush on mol change. 16 lanes x h4 per 32-node chunk.
__global__ void mol_pool_kernel(const _Float16* __restrict__ ns, const int* __restrict__ batch,
                                float* __restrict__ mol, int N) {
    int g = (blockIdx.x * blockDim.x + threadIdx.x) >> 4;
    int j = threadIdx.x & 15;
    int n0 = g * 32;
    if (n0 >= N) return;
    int n1 = min(n0 + 32, N);
    const h4* ns4 = (const h4*)ns;
    int cur = batch[n0];
    float ax = 0.f, ay = 0.f, az = 0.f, aw = 0.f;
    for (int n = n0; n < n1; ++n) {
        int b = batch[n];
        if (b != cur) {
            float* mp = &mol[(long long)cur * 64 + j * 4];
            atomicAdd(mp + 0, ax); atomicAdd(mp + 1, ay);
            atomicAdd(mp + 2, az); atomicAdd(mp + 3, aw);
            ax = ay = az = aw = 0.f; cur = b;
        }
        h4 vv = ns4[(long long)n * 16 + j];
        ax += (float)vv.x; ay += (float)vv.y; az += (float)vv.z; aw += (float)vv.w;
    }
    float* mp = &mol[(long long)cur * 64 + j * 4];
    atomicAdd(mp + 0, ax); atomicAdd(mp + 1, ay);
    atomicAdd(mp + 2, az); atomicAdd(mp + 3, aw);
}

__global__ void head_kernel(const float* __restrict__ mol, const float* __restrict__ W1,
                            const float* __restrict__ b1, const float* __restrict__ W2,
                            const float* __restrict__ b2, float* __restrict__ out) {
    int g = blockIdx.x;
    int j = threadIdx.x;   // 0..127
    float s = b1[j];
#pragma unroll
    for (int k = 0; k < 64; ++k) s = fmaf(mol[g * 64 + k], W1[k * 128 + j], s);
    s = fmaxf(s, 0.0f) * W2[j];
    __shared__ float red[128];
    red[j] = s;
    __syncthreads();
    for (int off = 64; off > 0; off >>= 1) {
        if (j < off) red[j] += red[j + off];
        __syncthreads();
    }
    if (j == 0) out[g] = red[0] + b2[0];
}

extern "C" void kernel_launch(void* const* d_in, const int* in_sizes, int n_in,
                              void* d_out, int out_size, void* d_ws, size_t ws_size,
                              hipStream_t stream) {
    const int*   x          = (const int*)d_in[0];
    const int*   eattr      = (const int*)d_in[1];
    const int*   ei         = (const int*)d_in[2];
    const int*   batch      = (const int*)d_in[3];
    const float* atom_table = (const float*)d_in[4];
    const float* bond_table = (const float*)d_in[5];
    const float* Wi         = (const float*)d_in[6];
    const float* bi         = (const float*)d_in[7];
    const float* Wu         = (const float*)d_in[8];
    const float* bu         = (const float*)d_in[9];
    const float* W1         = (const float*)d_in[10];
    const float* b1         = (const float*)d_in[11];
    const float* W2         = (const float*)d_in[12];
    const float* b2         = (const float*)d_in[13];

    const int N = in_sizes[0];      // 100000
    const int E = in_sizes[1];      // 1600000
    const int M = out_size;         // 2048
    const int K = (N + 63) >> BSHIFT;

    char* ws = (char*)d_ws;
    size_t off_b = 0;
    auto alloc = [&](size_t bytes) -> void* {
        void* p = ws + off_b;
        off_b = (off_b + bytes + 255) & ~(size_t)255;
        return p;
    };
    _Float16* bufA  = (_Float16*)alloc((size_t)N * MSG * 2);
    _Float16* bufB  = (_Float16*)alloc((size_t)N * MSG * 2);
    unsigned* packed = (unsigned*)alloc((size_t)E * 4);
    unsigned long long* aux = (unsigned long long*)alloc((size_t)E * 8);
    int*      cnt    = (int*)alloc((size_t)N * 4);
    int*      incl   = (int*)alloc((size_t)N * 4);
    int*      offs   = (int*)alloc((size_t)(N + 1) * 4);
    int*      bcur   = (int*)alloc((size_t)K * 4);
    int*      bsum   = (int*)alloc(1024 * 4);
    _Float16* tABi   = (_Float16*)alloc((size_t)NCOMBO * MSG * 2);
    _Float16* tABu   = (_Float16*)alloc((size_t)NCOMBO * MSG * 2);
    float*    mol    = (float*)alloc((size_t)M * MSG * 4);
    (void)ws_size; (void)n_in;

    // Combined tables (atom@W + bond@W + bias), one row per (x, eattr) combo.
    build_tab_kernel<<<(NCOMBO * MSG + 255) / 256, 256, 0, stream>>>(atom_table, bond_table, Wi, bi, tABi);
    build_tab_kernel<<<(NCOMBO * MSG + 255) / 256, 256, 0, stream>>>(atom_table, bond_table, Wu, bu, tABu);

    // ---- CSR by dst ----
    const int nb = (N + 1023) / 1024;
    hipMemsetAsync(cnt, 0, (size_t)N * 4, stream);
    hist_kernel<<<(E + 255) / 256, 256, 0, stream>>>(ei, E, cnt);
    scan1_kernel<<<nb, 1024, 0, stream>>>(cnt, incl, bsum, N);
    scan2_kernel<<<1, 64, 0, stream>>>(bsum, nb);
    scan3_kernel<<<nb, 1024, 0, stream>>>(incl, bsum, offs, N);
    binit_kernel<<<(K + 255) / 256, 256, 0, stream>>>(offs, bcur, K);
    bucket_scatter_kernel<<<(E + 255) / 256, 256, 0, stream>>>(ei, x, eattr, E, bcur, aux);
    bucket_place_kernel<<<K, 256, 0, stream>>>(aux, offs, packed, N);

    // ---- message passes (gather form, fused node-GEMM epilogue) ----
    const int gblocks = (int)(((long long)N * 16 + 255) / 256);
    const float* Wagg = Wu + 80 * MSG;
    gather_kernel<0><<<gblocks, 256, 0, stream>>>(packed, offs, tABi, nullptr, Wagg, bufA, N);
    gather_kernel<1><<<gblocks, 256, 0, stream>>>(packed, offs, tABu, bufA, Wagg, bufB, N);
    gather_kernel<1><<<gblocks, 256, 0, stream>>>(packed, offs, tABu, bufB, Wagg, bufA, N);
    gather_kernel<1><<<gblocks, 256, 0, stream>>>(packed, offs, tABu, bufA, Wagg, bufB, N);
    gather_kernel<2><<<gblocks, 256, 0, stream>>>(packed, offs, tABu, bufB, Wagg, bufA, N);

    // ---- readout ----
    hipMemsetAsync(mol, 0, (size_t)M * MSG * 4, stream);
    mol_pool_kernel<<<(((N + 31) / 32) * 16 + 255) / 256, 256, 0, stream>>>(bufA, batch, mol, N);
    head_kernel<<<M, 128, 0, stream>>>(mol, W1, b1, W2, b2, (float*)d_out);
}

// Round 5
// 434.283 us; speedup vs baseline: 1.4169x; 1.4169x over previous
//
#include <hip/hip_runtime.h>

#define MSG 64
#define NCOMBO 476   // 119 atom ids * 4 bond ids

typedef _Float16 h4 __attribute__((ext_vector_type(4)));

// tAB[c][i] = bias[i] + atom[c>>2] @ W[0:64] + bond[c&3] @ W[64:80]   (W ld=64), fp16 out
__global__ void build_tab_kernel(const float* __restrict__ atom, const float* __restrict__ bond,
                                 const float* __restrict__ W, const float* __restrict__ bias,
                                 _Float16* __restrict__ tAB) {
    int t = blockIdx.x * blockDim.x + threadIdx.x;
    if (t >= NCOMBO * MSG) return;
    int i = t & 63, c = t >> 6, xa = c >> 2, ea = c & 3;
    float s = bias[i];
    for (int k = 0; k < 64; ++k) s = fmaf(atom[xa * 64 + k], W[k * 64 + i], s);
    for (int k = 0; k < 16; ++k) s = fmaf(bond[ea * 16 + k], W[(64 + k) * 64 + i], s);
    tAB[t] = (_Float16)s;
}

__global__ void hist_kernel(const int* __restrict__ ei, int E, int* __restrict__ cnt) {
    int e = blockIdx.x * blockDim.x + threadIdx.x;
    if (e < E) atomicAdd(&cnt[ei[E + e]], 1);
}

// block-level inclusive scan (1024/block) + block sums
__global__ void scan1_kernel(const int* __restrict__ cnt, int* __restrict__ incl,
                             int* __restrict__ bsum, int N) {
    int i = blockIdx.x * 1024 + threadIdx.x;
    int v = (i < N) ? cnt[i] : 0;
    int lane = threadIdx.x & 63, w = threadIdx.x >> 6;
    int s = v;
    for (int off = 1; off < 64; off <<= 1) { int t = __shfl_up(s, off); if (lane >= off) s += t; }
    __shared__ int wsum[16];
    if (lane == 63) wsum[w] = s;
    __syncthreads();
    if (w == 0 && lane < 16) {
        int t = wsum[lane];
        for (int off = 1; off < 16; off <<= 1) { int u = __shfl_up(t, off); if (lane >= off) t += u; }
        wsum[lane] = t;
    }
    __syncthreads();
    if (w > 0) s += wsum[w - 1];
    if (i < N) incl[i] = s;
    if (threadIdx.x == 1023) bsum[blockIdx.x] = s;
}

__global__ void scan2_kernel(int* __restrict__ bsum, int nb) {
    if (threadIdx.x == 0 && blockIdx.x == 0) {
        int run = 0;
        for (int b = 0; b < nb; ++b) { int t = bsum[b]; bsum[b] = run; run += t; }
    }
}

__global__ void scan3_kernel(const int* __restrict__ incl, const int* __restrict__ bsum,
                             int* __restrict__ off, int N) {
    int i = blockIdx.x * 1024 + threadIdx.x;
    if (i < N) off[i + 1] = incl[i] + bsum[blockIdx.x];
    if (i == 0) off[0] = 0;
}

// Direct scatter, dst-sliced: block b serves slice (b&7); with round-robin
// block->XCD dispatch each slice's cursor range (~50KB) and packed window
// (~800KB) stay resident in ONE XCD's L2, so lines fill before write-back.
__global__ void scatter_sliced_kernel(const int* __restrict__ ei, const int* __restrict__ x,
                                      const int* __restrict__ eattr, int E,
                                      int* __restrict__ cursor, unsigned* __restrict__ packed,
                                      int slice_size) {
    int slice = blockIdx.x & 7;
    int lo = slice * slice_size, hi = lo + slice_size;
    int step = (gridDim.x >> 3) * blockDim.x;
    for (int e = (blockIdx.x >> 3) * blockDim.x + threadIdx.x; e < E; e += step) {
        int d = ei[E + e];
        if (d >= lo && d < hi) {
            int s = ei[e];
            int p = atomicAdd(&cursor[d], 1);
            packed[p] = (unsigned)s | ((unsigned)(x[s] * 4 + eattr[e]) << 17);
        }
    }
}

// 16 lanes per node (h4 per lane), 16 nodes per 256-thread block.
// acc = sum_{in-edges} relu(tAB[combo] + agg2[src]).   tAB/agg2/out in fp16, math fp32.
// MODE 0: no agg2, fused epilogue GEMM; MODE 1: agg2 + fused GEMM; MODE 2: agg2, raw out.
template <int MODE>
__global__ __launch_bounds__(256) void gather_kernel(
    const unsigned* __restrict__ packed, const int* __restrict__ off,
    const _Float16* __restrict__ tAB, const _Float16* __restrict__ agg2,
    const float* __restrict__ Wagg, _Float16* __restrict__ out, int N)
{
    __shared__ float Ws[64 * 64];
    __shared__ float rowbuf[16][68];   // stride 68 de-conflicts per-group broadcast
    if (MODE < 2)
        for (int idx = threadIdx.x; idx < 64 * 64; idx += 256) Ws[idx] = Wagg[idx];
    int t = blockIdx.x * 256 + threadIdx.x;
    int v = t >> 4;                    // node
    int j = threadIdx.x & 15;          // feature quad
    int w = threadIdx.x >> 4;          // group in block
    const h4* tAB4 = (const h4*)tAB;
    const h4* agg4 = (const h4*)agg2;
    float ax = 0.f, ay = 0.f, az = 0.f, aw = 0.f;
    if (v < N) {
        int e = off[v], end = off[v + 1];
        for (; e + 3 < end; e += 4) {
            unsigned p0 = packed[e], p1 = packed[e + 1], p2 = packed[e + 2], p3 = packed[e + 3];
            h4 t0 = tAB4[(p0 >> 17) * 16 + j];
            h4 t1 = tAB4[(p1 >> 17) * 16 + j];
            h4 t2 = tAB4[(p2 >> 17) * 16 + j];
            h4 t3 = tAB4[(p3 >> 17) * 16 + j];
            float m0x = (float)t0.x, m0y = (float)t0.y, m0z = (float)t0.z, m0w = (float)t0.w;
            float m1x = (float)t1.x, m1y = (float)t1.y, m1z = (float)t1.z, m1w = (float)t1.w;
            float m2x = (float)t2.x, m2y = (float)t2.y, m2z = (float)t2.z, m2w = (float)t2.w;
            float m3x = (float)t3.x, m3y = (float)t3.y, m3z = (float)t3.z, m3w = (float)t3.w;
            if (MODE) {
                h4 a0 = agg4[(p0 & 0x1FFFFu) * 16 + j];
                h4 a1 = agg4[(p1 & 0x1FFFFu) * 16 + j];
                h4 a2 = agg4[(p2 & 0x1FFFFu) * 16 + j];
                h4 a3 = agg4[(p3 & 0x1FFFFu) * 16 + j];
                m0x += (float)a0.x; m0y += (float)a0.y; m0z += (float)a0.z; m0w += (float)a0.w;
                m1x += (float)a1.x; m1y += (float)a1.y; m1z += (float)a1.z; m1w += (float)a1.w;
                m2x += (float)a2.x; m2y += (float)a2.y; m2z += (float)a2.z; m2w += (float)a2.w;
                m3x += (float)a3.x; m3y += (float)a3.y; m3z += (float)a3.z; m3w += (float)a3.w;
            }
            ax += fmaxf(m0x, 0.f) + fmaxf(m1x, 0.f) + fmaxf(m2x, 0.f) + fmaxf(m3x, 0.f);
            ay += fmaxf(m0y, 0.f) + fmaxf(m1y, 0.f) + fmaxf(m2y, 0.f) + fmaxf(m3y, 0.f);
            az += fmaxf(m0z, 0.f) + fmaxf(m1z, 0.f) + fmaxf(m2z, 0.f) + fmaxf(m3z, 0.f);
            aw += fmaxf(m0w, 0.f) + fmaxf(m1w, 0.f) + fmaxf(m2w, 0.f) + fmaxf(m3w, 0.f);
        }
        for (; e < end; ++e) {
            unsigned p0 = packed[e];
            h4 t0 = tAB4[(p0 >> 17) * 16 + j];
            float m0x = (float)t0.x, m0y = (float)t0.y, m0z = (float)t0.z, m0w = (float)t0.w;
            if (MODE) {
                h4 a0 = agg4[(p0 & 0x1FFFFu) * 16 + j];
                m0x += (float)a0.x; m0y += (float)a0.y; m0z += (float)a0.z; m0w += (float)a0.w;
            }
            ax += fmaxf(m0x, 0.f);
            ay += fmaxf(m0y, 0.f);
            az += fmaxf(m0z, 0.f);
            aw += fmaxf(m0w, 0.f);
        }
    }
    if (MODE == 2) {
        if (v < N) {
            h4 o; o.x = (_Float16)ax; o.y = (_Float16)ay; o.z = (_Float16)az; o.w = (_Float16)aw;
            ((h4*)out)[(long long)v * 16 + j] = o;
        }
        return;
    }
    rowbuf[w][j * 4 + 0] = ax;
    rowbuf[w][j * 4 + 1] = ay;
    rowbuf[w][j * 4 + 2] = az;
    rowbuf[w][j * 4 + 3] = aw;
    __syncthreads();
    if (v >= N) return;
    const float4* Ws4 = (const float4*)Ws;
    float sx = 0.f, sy = 0.f, sz = 0.f, sw = 0.f;
#pragma unroll
    for (int k = 0; k < 64; ++k) {
        float r = rowbuf[w][k];
        float4 wv = Ws4[k * 16 + j];
        sx = fmaf(r, wv.x, sx);
        sy = fmaf(r, wv.y, sy);
        sz = fmaf(r, wv.z, sz);
        sw = fmaf(r, wv.w, sw);
    }
    h4 o; o.x = (_Float16)sx; o.y = (_Float16)sy; o.z = (_Float16)sz; o.w = (_Float16)sw;
    ((h4*)out)[(long long)v * 16 + j] = o;
}

// batch is sorted: run-length accumulate, flush on mol change. 16 lanes x h4 per 32-node chunk.
__global__ void mol_pool_kernel(const _Float16* __restrict__ ns, const int* __restrict__ batch,
                                float* __restrict__ mol, int N) {
    int g = (blockIdx.x * blockDim.x + threadIdx.x) >> 4;
    int j = threadIdx.x & 15;
    int n0 = g * 32;
    if (n0 >= N) return;
    int n1 = min(n0 + 32, N);
    const h4* ns4 = (const h4*)ns;
    int cur = batch[n0];
    float ax = 0.f, ay = 0.f, az = 0.f, aw = 0.f;
    for (int n = n0; n < n1; ++n) {
        int b = batch[n];
        if (b != cur) {
            float* mp = &mol[(long long)cur * 64 + j * 4];
            atomicAdd(mp + 0, ax); atomicAdd(mp + 1, ay);
            atomicAdd(mp + 2, az); atomicAdd(mp + 3, aw);
            ax = ay = az = aw = 0.f; cur = b;
        }
        h4 vv = ns4[(long long)n * 16 + j];
        ax += (float)vv.x; ay += (float)vv.y; az += (float)vv.z; aw += (float)vv.w;
    }
    float* mp = &mol[(long long)cur * 64 + j * 4];
    atomicAdd(mp + 0, ax); atomicAdd(mp + 1, ay);
    atomicAdd(mp + 2, az); atomicAdd(mp + 3, aw);
}

__global__ void head_kernel(const float* __restrict__ mol, const float* __restrict__ W1,
                            const float* __restrict__ b1, const float* __restrict__ W2,
                            const float* __restrict__ b2, float* __restrict__ out) {
    int g = blockIdx.x;
    int j = threadIdx.x;   // 0..127
    float s = b1[j];
#pragma unroll
    for (int k = 0; k < 64; ++k) s = fmaf(mol[g * 64 + k], W1[k * 128 + j], s);
    s = fmaxf(s, 0.0f) * W2[j];
    __shared__ float red[128];
    red[j] = s;
    __syncthreads();
    for (int off = 64; off > 0; off >>= 1) {
        if (j < off) red[j] += red[j + off];
        __syncthreads();
    }
    if (j == 0) out[g] = red[0] + b2[0];
}

extern "C" void kernel_launch(void* const* d_in, const int* in_sizes, int n_in,
                              void* d_out, int out_size, void* d_ws, size_t ws_size,
                              hipStream_t stream) {
    const int*   x          = (const int*)d_in[0];
    const int*   eattr      = (const int*)d_in[1];
    const int*   ei         = (const int*)d_in[2];
    const int*   batch      = (const int*)d_in[3];
    const float* atom_table = (const float*)d_in[4];
    const float* bond_table = (const float*)d_in[5];
    const float* Wi         = (const float*)d_in[6];
    const float* bi         = (const float*)d_in[7];
    const float* Wu         = (const float*)d_in[8];
    const float* bu         = (const float*)d_in[9];
    const float* W1         = (const float*)d_in[10];
    const float* b1         = (const float*)d_in[11];
    const float* W2         = (const float*)d_in[12];
    const float* b2         = (const float*)d_in[13];

    const int N = in_sizes[0];      // 100000
    const int E = in_sizes[1];      // 1600000
    const int M = out_size;         // 2048

    char* ws = (char*)d_ws;
    size_t off_b = 0;
    auto alloc = [&](size_t bytes) -> void* {
        void* p = ws + off_b;
        off_b = (off_b + bytes + 255) & ~(size_t)255;
        return p;
    };
    _Float16* bufA  = (_Float16*)alloc((size_t)N * MSG * 2);
    _Float16* bufB  = (_Float16*)alloc((size_t)N * MSG * 2);
    unsigned* packed = (unsigned*)alloc((size_t)E * 4);
    int*      cnt    = (int*)alloc((size_t)N * 4);
    int*      incl   = (int*)alloc((size_t)N * 4);
    int*      offs   = (int*)alloc((size_t)(N + 1) * 4);
    int*      cursor = (int*)alloc((size_t)N * 4);
    int*      bsum   = (int*)alloc(1024 * 4);
    _Float16* tABi   = (_Float16*)alloc((size_t)NCOMBO * MSG * 2);
    _Float16* tABu   = (_Float16*)alloc((size_t)NCOMBO * MSG * 2);
    float*    mol    = (float*)alloc((size_t)M * MSG * 4);
    (void)ws_size; (void)n_in;

    // Combined tables (atom@W + bond@W + bias), one row per (x, eattr) combo.
    build_tab_kernel<<<(NCOMBO * MSG + 255) / 256, 256, 0, stream>>>(atom_table, bond_table, Wi, bi, tABi);
    build_tab_kernel<<<(NCOMBO * MSG + 255) / 256, 256, 0, stream>>>(atom_table, bond_table, Wu, bu, tABu);

    // ---- CSR by dst ----
    const int nb = (N + 1023) / 1024;
    hipMemsetAsync(cnt, 0, (size_t)N * 4, stream);
    hist_kernel<<<(E + 255) / 256, 256, 0, stream>>>(ei, E, cnt);
    scan1_kernel<<<nb, 1024, 0, stream>>>(cnt, incl, bsum, N);
    scan2_kernel<<<1, 64, 0, stream>>>(bsum, nb);
    scan3_kernel<<<nb, 1024, 0, stream>>>(incl, bsum, offs, N);
    hipMemcpyAsync(cursor, offs, (size_t)N * 4, hipMemcpyDeviceToDevice, stream);
    const int slice_size = (N + 7) / 8;
    scatter_sliced_kernel<<<8 * 512, 256, 0, stream>>>(ei, x, eattr, E, cursor, packed, slice_size);

    // ---- message passes (gather form, fused node-GEMM epilogue) ----
    const int gblocks = (int)(((long long)N * 16 + 255) / 256);
    const float* Wagg = Wu + 80 * MSG;
    gather_kernel<0><<<gblocks, 256, 0, stream>>>(packed, offs, tABi, nullptr, Wagg, bufA, N);
    gather_kernel<1><<<gblocks, 256, 0, stream>>>(packed, offs, tABu, bufA, Wagg, bufB, N);
    gather_kernel<1><<<gblocks, 256, 0, stream>>>(packed, offs, tABu, bufB, Wagg, bufA, N);
    gather_kernel<1><<<gblocks, 256, 0, stream>>>(packed, offs, tABu, bufA, Wagg, bufB, N);
    gather_kernel<2><<<gblocks, 256, 0, stream>>>(packed, offs, tABu, bufB, Wagg, bufA, N);

    // ---- readout ----
    hipMemsetAsync(mol, 0, (size_t)M * MSG * 4, stream);
    mol_pool_kernel<<<(((N + 31) / 32) * 16 + 255) / 256, 256, 0, stream>>>(bufA, batch, mol, N);
    head_kernel<<<M, 128, 0, stream>>>(mol, W1, b1, W2, b2, (float*)d_out);
}